// Round 1
// baseline (22.488 us; speedup 1.0000x reference)
//
#include <hip/hip_runtime.h>

#define NBATCH 2048
#define NCONF  256
#define NUP    8
#define NDOWN  8
#define NMO    40
#define NELEC  16

// 8x8 determinant via fully-unrolled LU with partial pivoting.
// All loop indices are compile-time after unroll -> matrix stays in VGPRs
// (rule: runtime-indexed register arrays go to scratch).
__device__ __forceinline__ float det8(float a[8][8]) {
    float det = 1.0f;
    #pragma unroll
    for (int k = 0; k < 8; ++k) {
        // Partial pivot: bubble the row with max |a[i][k]| into row k via
        // predicated swaps (only columns >= k matter). Each real swap flips sign.
        #pragma unroll
        for (int i = k + 1; i < 8; ++i) {
            const bool sw = fabsf(a[i][k]) > fabsf(a[k][k]);
            #pragma unroll
            for (int j = k; j < 8; ++j) {
                const float tk = a[k][j];
                const float ti = a[i][j];
                a[k][j] = sw ? ti : tk;
                a[i][j] = sw ? tk : ti;
            }
            det = sw ? -det : det;
        }
        const float piv = a[k][k];
        det *= piv;
        const float inv = 1.0f / piv;
        #pragma unroll
        for (int i = k + 1; i < 8; ++i) {
            const float f = a[i][k] * inv;
            #pragma unroll
            for (int j = k + 1; j < 8; ++j) {
                a[i][j] = fmaf(-f, a[k][j], a[i][j]);
            }
        }
    }
    return det;
}

__global__ __launch_bounds__(NCONF) void slater_pool_kernel(
    const float* __restrict__ mo,     // (NBATCH, NELEC, NMO)
    const int*   __restrict__ cup,    // (NCONF, NUP)
    const int*   __restrict__ cdown,  // (NCONF, NDOWN)
    float*       __restrict__ out)    // (NBATCH, NCONF)
{
    __shared__ float smo[NELEC * NMO];  // 2560 B: this batch's orbitals

    const int b = blockIdx.x;
    const int c = threadIdx.x;

    // Stage mo[b] into LDS, coalesced.
    for (int i = threadIdx.x; i < NELEC * NMO; i += NCONF) {
        smo[i] = mo[b * (NELEC * NMO) + i];
    }
    __syncthreads();

    float a[8][8];
    int   idx[8];

    // --- spin-up determinant ---
    #pragma unroll
    for (int j = 0; j < 8; ++j) idx[j] = cup[c * NUP + j];
    #pragma unroll
    for (int i = 0; i < 8; ++i) {
        #pragma unroll
        for (int j = 0; j < 8; ++j) {
            a[i][j] = smo[i * NMO + idx[j]];
        }
    }
    const float det_up = det8(a);

    // --- spin-down determinant ---
    #pragma unroll
    for (int j = 0; j < 8; ++j) idx[j] = cdown[c * NDOWN + j];
    #pragma unroll
    for (int i = 0; i < 8; ++i) {
        #pragma unroll
        for (int j = 0; j < 8; ++j) {
            a[i][j] = smo[(NUP + i) * NMO + idx[j]];
        }
    }
    const float det_dn = det8(a);

    out[b * NCONF + c] = det_up * det_dn;
}

extern "C" void kernel_launch(void* const* d_in, const int* in_sizes, int n_in,
                              void* d_out, int out_size, void* d_ws, size_t ws_size,
                              hipStream_t stream) {
    const float* mo    = (const float*)d_in[0];
    const int*   cup   = (const int*)d_in[1];
    const int*   cdown = (const int*)d_in[2];
    float*       out   = (float*)d_out;

    slater_pool_kernel<<<NBATCH, NCONF, 0, stream>>>(mo, cup, cdown, out);
}

// Round 2
// 22.392 us; speedup vs baseline: 1.0043x; 1.0043x over previous
//
#include <hip/hip_runtime.h>

#define NBATCH 2048
#define NCONF  256
#define NUP    8
#define NDOWN  8
#define NMO    40
#define NELEC  16
#define SSTRIDE 20   // padded column stride (floats): 80 B, 16B-aligned,
                     // idx*20 mod 32 covers all 32 banks in groups of 4

// 8x8 determinant via fully-unrolled LU with partial pivoting.
// All loop indices compile-time after unroll -> matrix stays in VGPRs.
__device__ __forceinline__ float det8(float a[8][8]) {
    float det = 1.0f;
    #pragma unroll
    for (int k = 0; k < 8; ++k) {
        #pragma unroll
        for (int i = k + 1; i < 8; ++i) {
            const bool sw = fabsf(a[i][k]) > fabsf(a[k][k]);
            #pragma unroll
            for (int j = k; j < 8; ++j) {
                const float tk = a[k][j];
                const float ti = a[i][j];
                a[k][j] = sw ? ti : tk;
                a[i][j] = sw ? tk : ti;
            }
            det = sw ? -det : det;
        }
        const float piv = a[k][k];
        det *= piv;
        const float inv = 1.0f / piv;
        #pragma unroll
        for (int i = k + 1; i < 8; ++i) {
            const float f = a[i][k] * inv;
            #pragma unroll
            for (int j = k + 1; j < 8; ++j) {
                a[i][j] = fmaf(-f, a[k][j], a[i][j]);
            }
        }
    }
    return det;
}

__global__ __launch_bounds__(NCONF) void slater_pool_kernel(
    const float* __restrict__ mo,     // (NBATCH, NELEC, NMO)
    const int*   __restrict__ cup,    // (NCONF, NUP)
    const int*   __restrict__ cdown,  // (NCONF, NDOWN)
    float*       __restrict__ out)    // (NBATCH, NCONF)
{
    // Transposed + padded staging: smoT[m * SSTRIDE + e] = mo[b, e, m].
    // A Slater-matrix column (fixed orbital m, electrons e) is contiguous ->
    // gather with ds_read_b128 pairs instead of 8 scalar ds_read_b32.
    __shared__ __align__(16) float smoT[NMO * SSTRIDE];  // 3200 B

    const int b = blockIdx.x;
    const int c = threadIdx.x;

    // Stage with transpose (coalesced global reads, few scattered LDS writes).
    #pragma unroll
    for (int t = threadIdx.x; t < NELEC * NMO; t += NCONF) {
        const float v = mo[b * (NELEC * NMO) + t];
        const int e = t / NMO;
        const int m = t - e * NMO;
        smoT[m * SSTRIDE + e] = v;
    }
    __syncthreads();

    float a[8][8];

    // --- spin-up determinant (electrons 0..7) ---
    const int4 u0 = ((const int4*)cup)[c * 2 + 0];
    const int4 u1 = ((const int4*)cup)[c * 2 + 1];
    int idx[8] = {u0.x, u0.y, u0.z, u0.w, u1.x, u1.y, u1.z, u1.w};
    #pragma unroll
    for (int j = 0; j < 8; ++j) {
        const float4* col = (const float4*)&smoT[idx[j] * SSTRIDE];
        const float4 lo = col[0];
        const float4 hi = col[1];
        a[0][j] = lo.x; a[1][j] = lo.y; a[2][j] = lo.z; a[3][j] = lo.w;
        a[4][j] = hi.x; a[5][j] = hi.y; a[6][j] = hi.z; a[7][j] = hi.w;
    }
    const float det_up = det8(a);

    // --- spin-down determinant (electrons 8..15) ---
    const int4 d0 = ((const int4*)cdown)[c * 2 + 0];
    const int4 d1 = ((const int4*)cdown)[c * 2 + 1];
    int jdx[8] = {d0.x, d0.y, d0.z, d0.w, d1.x, d1.y, d1.z, d1.w};
    #pragma unroll
    for (int j = 0; j < 8; ++j) {
        const float4* col = (const float4*)&smoT[jdx[j] * SSTRIDE + 8];
        const float4 lo = col[0];
        const float4 hi = col[1];
        a[0][j] = lo.x; a[1][j] = lo.y; a[2][j] = lo.z; a[3][j] = lo.w;
        a[4][j] = hi.x; a[5][j] = hi.y; a[6][j] = hi.z; a[7][j] = hi.w;
    }
    const float det_dn = det8(a);

    out[b * NCONF + c] = det_up * det_dn;
}

extern "C" void kernel_launch(void* const* d_in, const int* in_sizes, int n_in,
                              void* d_out, int out_size, void* d_ws, size_t ws_size,
                              hipStream_t stream) {
    const float* mo    = (const float*)d_in[0];
    const int*   cup   = (const int*)d_in[1];
    const int*   cdown = (const int*)d_in[2];
    float*       out   = (float*)d_out;

    slater_pool_kernel<<<NBATCH, NCONF, 0, stream>>>(mo, cup, cdown, out);
}

// Round 3
// 21.322 us; speedup vs baseline: 1.0547x; 1.0502x over previous
//
#include <hip/hip_runtime.h>

#define NBATCH 2048
#define NCONF  256
#define NMO    40
#define NELEC  16
#define SSTRIDE 20   // padded column stride (floats): 80 B, 16B-aligned

// 8x8 determinant via fully-unrolled LU with partial pivoting.
// All loop indices compile-time after unroll -> matrix stays in VGPRs.
__device__ __forceinline__ float det8(float a[8][8]) {
    float det = 1.0f;
    #pragma unroll
    for (int k = 0; k < 8; ++k) {
        #pragma unroll
        for (int i = k + 1; i < 8; ++i) {
            const bool sw = fabsf(a[i][k]) > fabsf(a[k][k]);
            #pragma unroll
            for (int j = k; j < 8; ++j) {
                const float tk = a[k][j];
                const float ti = a[i][j];
                a[k][j] = sw ? ti : tk;
                a[i][j] = sw ? tk : ti;
            }
            det = sw ? -det : det;
        }
        const float piv = a[k][k];
        det *= piv;
        // v_rcp_f32: ~1 ulp approx reciprocal; avoids the ~10-op exact-div
        // sequence. 8 uses/det -> ~2e-6 relative error, negligible vs threshold.
        const float inv = __builtin_amdgcn_rcpf(piv);
        #pragma unroll
        for (int i = k + 1; i < 8; ++i) {
            const float f = a[i][k] * inv;
            #pragma unroll
            for (int j = k + 1; j < 8; ++j) {
                a[i][j] = fmaf(-f, a[k][j], a[i][j]);
            }
        }
    }
    return det;
}

// One thread = ONE 8x8 determinant (spin up or down). Thread pairs (2c, 2c+1)
// handle config c's up/down dets; combine via shfl_xor. Halves the per-thread
// serial dependency chain and register pressure vs 2 dets/thread.
__global__ __launch_bounds__(512) void slater_pool_kernel(
    const float* __restrict__ mo,     // (NBATCH, NELEC, NMO)
    const int*   __restrict__ cup,    // (NCONF, 8)
    const int*   __restrict__ cdown,  // (NCONF, 8)
    float*       __restrict__ out)    // (NBATCH, NCONF)
{
    // Transposed + padded staging: smoT[m * SSTRIDE + e] = mo[b, e, m].
    __shared__ __align__(16) float smoT[NMO * SSTRIDE];  // 3200 B

    const int b   = blockIdx.x;
    const int tid = threadIdx.x;

    for (int t = tid; t < NELEC * NMO; t += 512) {
        const float v = mo[b * (NELEC * NMO) + t];
        const int e = t / NMO;
        const int m = t - e * NMO;
        smoT[m * SSTRIDE + e] = v;
    }
    __syncthreads();

    const int c    = tid >> 1;   // config index 0..255
    const int spin = tid & 1;    // 0 = up, 1 = down

    const int* cfg = spin ? cdown : cup;
    const int4 i0 = ((const int4*)cfg)[c * 2 + 0];
    const int4 i1 = ((const int4*)cfg)[c * 2 + 1];
    const int idx[8] = {i0.x, i0.y, i0.z, i0.w, i1.x, i1.y, i1.z, i1.w};
    const int ebase = spin << 3;  // electron row offset: 0 or 8

    float a[8][8];
    #pragma unroll
    for (int j = 0; j < 8; ++j) {
        const float4* col = (const float4*)&smoT[idx[j] * SSTRIDE + ebase];
        const float4 lo = col[0];
        const float4 hi = col[1];
        a[0][j] = lo.x; a[1][j] = lo.y; a[2][j] = lo.z; a[3][j] = lo.w;
        a[4][j] = hi.x; a[5][j] = hi.y; a[6][j] = hi.z; a[7][j] = hi.w;
    }

    const float det   = det8(a);
    const float other = __shfl_xor(det, 1);
    if (spin == 0) {
        out[b * NCONF + c] = det * other;
    }
}

extern "C" void kernel_launch(void* const* d_in, const int* in_sizes, int n_in,
                              void* d_out, int out_size, void* d_ws, size_t ws_size,
                              hipStream_t stream) {
    const float* mo    = (const float*)d_in[0];
    const int*   cup   = (const int*)d_in[1];
    const int*   cdown = (const int*)d_in[2];
    float*       out   = (float*)d_out;

    slater_pool_kernel<<<NBATCH, 512, 0, stream>>>(mo, cup, cdown, out);
}

// Round 4
// 20.757 us; speedup vs baseline: 1.0834x; 1.0272x over previous
//
#include <hip/hip_runtime.h>

#define NBATCH 2048
#define NCONF  256
#define NMO    40
#define NELEC  16
#define SSTRIDE 20           // padded column stride (floats): 80 B, 16B-aligned
#define GROWTH_LIMIT 4096.0f // max |multiplier| before falling back to pivoted LU
#define PIV_FLOOR    1e-30f  // degenerate-pivot guard (also catches piv==0 -> NaN paths)

// Fast path: 8x8 LU WITHOUT pivoting (~220 VALU ops, no swap network).
// Tracks max|multiplier| and min|pivot| so callers can detect when numerical
// growth requires the safe pivoted fallback.
__device__ __forceinline__ float det8_nopivot(float a[8][8], float& mf, float& mp) {
    float det = 1.0f;
    mf = 0.0f;
    mp = 3.4e38f;
    #pragma unroll
    for (int k = 0; k < 8; ++k) {
        const float piv = a[k][k];
        det *= piv;
        mp = fminf(mp, fabsf(piv));
        const float inv = __builtin_amdgcn_rcpf(piv);  // v_rcp_f32
        #pragma unroll
        for (int i = k + 1; i < 8; ++i) {
            const float f = a[i][k] * inv;
            mf = fmaxf(mf, fabsf(f));
            #pragma unroll
            for (int j = k + 1; j < 8; ++j) {
                a[i][j] = fmaf(-f, a[k][j], a[i][j]);
            }
        }
    }
    return det;
}

// Safe path: fully-unrolled LU with partial pivoting (proven absmax 512).
__device__ __forceinline__ float det8_pivoted(float a[8][8]) {
    float det = 1.0f;
    #pragma unroll
    for (int k = 0; k < 8; ++k) {
        #pragma unroll
        for (int i = k + 1; i < 8; ++i) {
            const bool sw = fabsf(a[i][k]) > fabsf(a[k][k]);
            #pragma unroll
            for (int j = k; j < 8; ++j) {
                const float tk = a[k][j];
                const float ti = a[i][j];
                a[k][j] = sw ? ti : tk;
                a[i][j] = sw ? tk : ti;
            }
            det = sw ? -det : det;
        }
        const float piv = a[k][k];
        det *= piv;
        const float inv = __builtin_amdgcn_rcpf(piv);
        #pragma unroll
        for (int i = k + 1; i < 8; ++i) {
            const float f = a[i][k] * inv;
            #pragma unroll
            for (int j = k + 1; j < 8; ++j) {
                a[i][j] = fmaf(-f, a[k][j], a[i][j]);
            }
        }
    }
    return det;
}

__device__ __forceinline__ void gather8(const float* __restrict__ smoT,
                                        const int idx[8], int ebase,
                                        float a[8][8]) {
    #pragma unroll
    for (int j = 0; j < 8; ++j) {
        const float4* col = (const float4*)&smoT[idx[j] * SSTRIDE + ebase];
        const float4 lo = col[0];
        const float4 hi = col[1];
        a[0][j] = lo.x; a[1][j] = lo.y; a[2][j] = lo.z; a[3][j] = lo.w;
        a[4][j] = hi.x; a[5][j] = hi.y; a[6][j] = hi.z; a[7][j] = hi.w;
    }
}

// One thread = ONE 8x8 determinant. Thread pairs (2c, 2c+1) = config c's
// up/down dets; combined via shfl_xor.
__global__ __launch_bounds__(512) void slater_pool_kernel(
    const float* __restrict__ mo,     // (NBATCH, NELEC, NMO)
    const int*   __restrict__ cup,    // (NCONF, 8)
    const int*   __restrict__ cdown,  // (NCONF, 8)
    float*       __restrict__ out)    // (NBATCH, NCONF)
{
    // Transposed + padded staging: smoT[m * SSTRIDE + e] = mo[b, e, m].
    __shared__ __align__(16) float smoT[NMO * SSTRIDE];  // 3200 B

    const int b   = blockIdx.x;
    const int tid = threadIdx.x;

    for (int t = tid; t < NELEC * NMO; t += 512) {
        const float v = mo[b * (NELEC * NMO) + t];
        const int e = t / NMO;
        const int m = t - e * NMO;
        smoT[m * SSTRIDE + e] = v;
    }
    __syncthreads();

    const int c    = tid >> 1;   // config index 0..255
    const int spin = tid & 1;    // 0 = up, 1 = down

    const int* cfg = spin ? cdown : cup;
    const int4 i0 = ((const int4*)cfg)[c * 2 + 0];
    const int4 i1 = ((const int4*)cfg)[c * 2 + 1];
    const int idx[8] = {i0.x, i0.y, i0.z, i0.w, i1.x, i1.y, i1.z, i1.w};
    const int ebase = spin << 3;  // electron row offset: 0 or 8

    float a[8][8];
    gather8(smoT, idx, ebase, a);

    float mf, mp;
    float det = det8_nopivot(a, mf, mp);

    // Fallback: growth too large, degenerate pivot, or NaN crept in
    // (NaN fails both "<=" comparisons -> flagged). Re-gather (LDS intact)
    // and redo with partial pivoting. Rare: ~0.4% of dets.
    if (!(mf <= GROWTH_LIMIT) || !(mp >= PIV_FLOOR)) {
        gather8(smoT, idx, ebase, a);
        det = det8_pivoted(a);
    }

    const float other = __shfl_xor(det, 1);
    if (spin == 0) {
        out[b * NCONF + c] = det * other;
    }
}

extern "C" void kernel_launch(void* const* d_in, const int* in_sizes, int n_in,
                              void* d_out, int out_size, void* d_ws, size_t ws_size,
                              hipStream_t stream) {
    const float* mo    = (const float*)d_in[0];
    const int*   cup   = (const int*)d_in[1];
    const int*   cdown = (const int*)d_in[2];
    float*       out   = (float*)d_out;

    slater_pool_kernel<<<NBATCH, 512, 0, stream>>>(mo, cup, cdown, out);
}